// Round 4
// baseline (684.111 us; speedup 1.0000x reference)
//
#include <hip/hip_runtime.h>

// Problem: x [16, 512, 512, 32] f32 -> out [16, 512, 512, 1] f32
// out[b,h,w] = max over shifts S = {(0,0),(0,1),(1,0),(1,1),(0,2),(2,0),(2,2)}
//              of M[b, h-di, w-dj],  M = channel-max of x, OOB -> 0 (zero pad).
//
// v3: two-kernel decomposition (one structural change vs the 678-us v1).
//  Kernel A: M = channel-max(x) -> workspace. Lane t loads float4 at base+16t:
//    every wave load is 1024 B fully contiguous (the 6.29 TB/s pattern), vs
//    v1's 16 B/lane at 128-B stride (64 partial sectors per instruction).
//    8-lane shfl_xor reduce, no LDS, no barrier, no halo. Floor ~88 us.
//  Kernel B: 7-shift stencil max over M (16.8 MB): 4 outputs/thread, 6 aligned
//    float4 loads from 3 rows, L1 covers the overlap. ~10-15 us.
// Traffic: A = 537 MB R + 16.8 MB W; B = ~20 MB R + 16.8 MB W. Floor ~96 us.

#define HH 512
#define WW 512
#define CC 32

// ---- Kernel A: channel-max, fully-coalesced ----
// One pixel = 32 f32 = 8 float4 = 8 consecutive lanes; 64 lanes = 8 pixels
// per wave instruction, 1024 B dense.
__global__ __launch_bounds__(256) void chanmax_kernel(
    const float4* __restrict__ x4, float* __restrict__ M, int nf4) {
  const int tid = threadIdx.x;
  const int stride = gridDim.x * 256;
  for (int f = blockIdx.x * 256 + tid; f < nf4; f += stride) {
    const float4 v = x4[f];
    float m = fmaxf(fmaxf(v.x, v.y), fmaxf(v.z, v.w));
    // reduce across the 8 lanes holding this pixel (xor 1,2,4 stay in-octet)
    m = fmaxf(m, __shfl_xor(m, 1));
    m = fmaxf(m, __shfl_xor(m, 2));
    m = fmaxf(m, __shfl_xor(m, 4));
    if ((tid & 7) == 0) M[f >> 3] = m;  // 8 octet-leads -> 8 consecutive floats
  }
}

// ---- Kernel B: 7-way backward-shift max over M ----
// out[h,w] = max( M[h][w-2..w], M[h-1][w-1..w], M[h-2][w], M[h-2][w-2] ), OOB->0.
// Thread g -> 4 outputs at row bh = g>>7, cols 4*(g&127). Needs cols c0-2..c0+3
// of rows h-2..h: two aligned float4 loads per row (c4-1, c4).
__global__ __launch_bounds__(256) void shiftmax_kernel(
    const float* __restrict__ M, float* __restrict__ out, int total4) {
  const int g = blockIdx.x * 256 + threadIdx.x;
  if (g >= total4) return;
  const int c4 = g & (WW / 4 - 1);      // float4 col index
  const int bh = g >> 7;                // b*HH + h
  const int h  = bh & (HH - 1);

  const float4* row2 = (const float4*)M + (size_t)bh * (WW / 4);  // row h
  const float4* row1 = row2 - WW / 4;                             // row h-1
  const float4* row0 = row2 - 2 * (WW / 4);                       // row h-2

  const float4 z = make_float4(0.f, 0.f, 0.f, 0.f);
  const bool cg = (c4 > 0);
  const float4 b2 = row2[c4];
  const float4 a2 = cg ? row2[c4 - 1] : z;
  const float4 b1 = (h > 0) ? row1[c4] : z;
  const float4 a1 = (h > 0 && cg) ? row1[c4 - 1] : z;
  const float4 b0 = (h > 1) ? row0[c4] : z;
  const float4 a0 = (h > 1 && cg) ? row0[c4 - 1] : z;

  // cl[j] = col c0-2+j ; j = k+2 -> col w, k+1 -> w-1, k -> w-2 for output k
  const float c2[6] = {a2.z, a2.w, b2.x, b2.y, b2.z, b2.w};  // row h
  const float c1[6] = {a1.z, a1.w, b1.x, b1.y, b1.z, b1.w};  // row h-1
  const float c0_[6] = {a0.z, a0.w, b0.x, b0.y, b0.z, b0.w}; // row h-2

  float4 v;
  float* vp = &v.x;
#pragma unroll
  for (int k = 0; k < 4; ++k) {
    const float t2 = fmaxf(fmaxf(c2[k], c2[k + 1]), c2[k + 2]);  // dj=2,1,0
    const float t1 = fmaxf(c1[k + 1], c1[k + 2]);                // dj=1,0
    const float t0 = fmaxf(c0_[k], c0_[k + 2]);                  // dj=2,0
    vp[k] = fmaxf(fmaxf(t2, t1), t0);
  }
  ((float4*)out)[g] = v;
}

extern "C" void kernel_launch(void* const* d_in, const int* in_sizes, int n_in,
                              void* d_out, int out_size, void* d_ws, size_t ws_size,
                              hipStream_t stream) {
  const float* x = (const float*)d_in[0];
  float* out = (float*)d_out;
  float* M = (float*)d_ws;                 // 16.8 MB of the workspace

  const int nfloat = in_sizes[0];          // B*H*W*C
  const int nf4 = nfloat / 4;              // float4 count (33.5M)
  const int npix = nfloat / CC;            // B*H*W   (4.19M)
  const int total4 = npix / 4;             // B-kernel threads (1.05M)

  chanmax_kernel<<<8192, 256, 0, stream>>>((const float4*)x, M, nf4);
  const int blocksB = (total4 + 255) / 256;  // 4096
  shiftmax_kernel<<<blocksB, 256, 0, stream>>>(M, out, total4);
}